// Round 10
// baseline (541.579 us; speedup 1.0000x reference)
//
#include <hip/hip_runtime.h>

using u16 = unsigned short;
using u32 = unsigned int;

typedef __bf16 bf16x8 __attribute__((ext_vector_type(8)));
typedef float f32x4 __attribute__((ext_vector_type(4)));

#define M32 32768   // real tokens: 8*64*64 (no window padding anywhere)

__device__ __forceinline__ u16 f2bf(float f) {
  u32 u = __float_as_uint(f);
  u += 0x7fffu + ((u >> 16) & 1u);   // RNE
  return (u16)(u >> 16);
}
__device__ __forceinline__ u32 cvtpk(float a, float b) {   // HW RNE pair convert (lo=a, hi=b)
  u32 r; asm("v_cvt_pk_bf16_f32 %0, %1, %2" : "=v"(r) : "v"(a), "v"(b)); return r;
}
__device__ __forceinline__ float bflo(u32 w) { return __uint_as_float(w << 16); }
__device__ __forceinline__ float bfhi(u32 w) { return __uint_as_float(w & 0xffff0000u); }

__device__ __forceinline__ float exp2h(float x) {          // raw v_exp_f32 (computes 2^x)
#if __has_builtin(__builtin_amdgcn_exp2f)
  return __builtin_amdgcn_exp2f(x);
#else
  float e; asm("v_exp_f32 %0, %1\n\ts_nop 0" : "=v"(e) : "v"(x)); return e;
#endif
}

__device__ __forceinline__ void async16(const void* g, void* l) {
  __builtin_amdgcn_global_load_lds((const __attribute__((address_space(1))) void*)g,
                                   (__attribute__((address_space(3))) void*)l, 16, 0, 0);
}

union frag { uint4 u; bf16x8 b; };

// ---------------- prep: weights fp32 -> bf16, rope cos/sin table ----------------
__global__ __launch_bounds__(256) void prep_w(const float* __restrict__ qw,
                                              const float* __restrict__ pw,
                                              u16* __restrict__ qwb, u16* __restrict__ pwb,
                                              float2* __restrict__ cs) {
  int i = blockIdx.x * 256 + threadIdx.x;
  if (i < 2304 * 768) qwb[i] = f2bf(qw[i]);
  if (i < 768 * 768)  pwb[i] = f2bf(pw[i]);
  if (i < 196 * 32) {
    int t = i >> 5, f = i & 31;
    float fr = powf(10000.f, -(float)(f & 15) * (1.f / 16.f));
    float ang = (f < 16 ? (float)(t % 14) : (float)(t / 14)) * fr;
    cs[i] = make_float2(cosf(ang), sinf(ang));
  }
}

// ---------------- NT GEMM (128x128, BK=32, 2-phase dbuf + conflict-free LDS map) ----------------
// R10: R7 schedule + R2's subtiled-swizzled LDS layout (empirically 0 bank
// conflicts there; R5 proved granule-XOR within linear 64B rows CANNOT fix it).
// granule G(row,g) = (row>>4)*64 + (row&15)*4 + (g ^ (((row>>3)&1)<<1)); staged
// as linear global_load_lds dest + INVERSE-swizzled global source (rule 21);
// frag reads use the per-lane-constant XOR offset. EPI0 A-path (regs->ds_write)
// writes the swizzled dest directly, placed AFTER the MFMAs (scheduling slack).
//  EPI=0: A = x fp32, reg-staged + v_cvt_pk_bf16_f32; C = qkvb bf16 linear.
//  EPI=1: A = ao bf16 via global_load_lds; C = out fp32 linear.
// T1 XCD-bijective chunk swizzle, n innermost.
template<int EPI>
__global__ __launch_bounds__(256) void gemm_bt(
    const void* __restrict__ Av, const u16* __restrict__ B,
    const float* __restrict__ bias, u16* __restrict__ Cb,
    float* __restrict__ Cf, int K, int N, int NTI)
{
  __shared__ u16 As[2][128 * 32];
  __shared__ u16 Bs[2][128 * 32];

  const int nwg = gridDim.x;
  const int orig = blockIdx.x;
  const int q = nwg >> 3, r = nwg & 7;
  const int xcd = orig & 7, loc = orig >> 3;
  const int wg = (xcd < r ? xcd * (q + 1) : r * (q + 1) + (xcd - r) * q) + loc;
  const int m0 = (wg / NTI) * 128;
  const int n0 = (wg % NTI) * 128;

  const int tid = threadIdx.x;
  const int lane = tid & 63;
  const int wv = tid >> 6;
  const int wm = wv >> 1, wn = wv & 1;
  const int lr = lane & 15, lq = lane >> 4;

  // staging geometry: LDS-linear granule L = c*256+tid (16B), dest byte L*16.
  // inverse map: row = (L>>6)*16 + ((tid>>2)&15), src col-granule = (tid&3)^(((tid>>5)&1)<<1)
  const int srow0 = ((tid >> 6) << 4) + ((tid >> 2) & 15);
  const int sgsw  = ((tid & 3) ^ (((tid >> 5) & 1) << 1)) * 8;
  const u16* B0 = B + (size_t)(n0 + srow0) * K + sgsw;
  const u16* Ab0 = (const u16*)Av + (size_t)(m0 + srow0) * K + sgsw;      // EPI1
  // EPI0 A: plain source rows tid>>2 (+64), col (tid&3)*8; swizzled LDS dest.
  const float* Af0 = (const float*)Av + (size_t)(m0 + (tid >> 2)) * K + (tid & 3) * 8;
  const int dA = (((tid >> 6) * 64) + ((tid >> 2) & 15) * 4 +
                  ((tid & 3) ^ (((tid >> 5) & 1) << 1))) * 8;             // elems; +2048 for row+64

  // frag-read offset (elems) within a rowblock: XOR'd granule select
  const int fro = lr * 32 + ((lq ^ (((lr >> 3) & 1) << 1)) << 3);

  // prologue: tile 0 -> buf 0
  async16(B0, (void*)(Bs[0] + tid * 8));
  async16(B0 + (size_t)64 * K, (void*)(Bs[0] + 2048 + tid * 8));
  if constexpr (EPI == 0) {
    float4 a0 = *(const float4*)(Af0);
    float4 a1 = *(const float4*)(Af0 + 4);
    float4 a2 = *(const float4*)(Af0 + (size_t)64 * K);
    float4 a3 = *(const float4*)(Af0 + (size_t)64 * K + 4);
    *(uint4*)(As[0] + dA) =
        make_uint4(cvtpk(a0.x, a0.y), cvtpk(a0.z, a0.w), cvtpk(a1.x, a1.y), cvtpk(a1.z, a1.w));
    *(uint4*)(As[0] + 2048 + dA) =
        make_uint4(cvtpk(a2.x, a2.y), cvtpk(a2.z, a2.w), cvtpk(a3.x, a3.y), cvtpk(a3.z, a3.w));
  } else {
    async16(Ab0, (void*)(As[0] + tid * 8));
    async16(Ab0 + (size_t)64 * K, (void*)(As[0] + 2048 + tid * 8));
  }
  __syncthreads();

  f32x4 acc[4][4];
#pragma unroll
  for (int i = 0; i < 4; i++)
#pragma unroll
    for (int j = 0; j < 4; j++)
      acc[i][j] = f32x4{0.f, 0.f, 0.f, 0.f};

  const int NT = K / 32;
  for (int t = 0; t < NT; ++t) {
    const int cur = t & 1;
    const u16* Asc = As[cur];
    const u16* Bsc = Bs[cur];
    u16* Asn = As[cur ^ 1];
    u16* Bsn = Bs[cur ^ 1];
    const bool pre = (t + 1) < NT;
    const int k1 = (t + 1) * 32;

    float4 a0, a1, a2, a3;
    if (pre) {
      async16(B0 + k1, (void*)(Bsn + tid * 8));
      async16(B0 + (size_t)64 * K + k1, (void*)(Bsn + 2048 + tid * 8));
      if constexpr (EPI == 0) {
        a0 = *(const float4*)(Af0 + k1);
        a1 = *(const float4*)(Af0 + k1 + 4);
        a2 = *(const float4*)(Af0 + (size_t)64 * K + k1);
        a3 = *(const float4*)(Af0 + (size_t)64 * K + k1 + 4);
      } else {
        async16(Ab0 + k1, (void*)(Asn + tid * 8));
        async16(Ab0 + (size_t)64 * K + k1, (void*)(Asn + 2048 + tid * 8));
      }
    }

    frag af[4], bg[4];
#pragma unroll
    for (int i = 0; i < 4; i++) {
      af[i].u = *(const uint4*)(Asc + (wm * 4 + i) * 512 + fro);
      bg[i].u = *(const uint4*)(Bsc + (wn * 4 + i) * 512 + fro);
    }

#pragma unroll
    for (int i = 0; i < 4; i++)
#pragma unroll
      for (int j = 0; j < 4; j++)
        acc[i][j] = __builtin_amdgcn_mfma_f32_16x16x32_bf16(af[i].b, bg[j].b, acc[i][j], 0, 0, 0);

    if (pre && EPI == 0) {
      *(uint4*)(Asn + dA) =
          make_uint4(cvtpk(a0.x, a0.y), cvtpk(a0.z, a0.w), cvtpk(a1.x, a1.y), cvtpk(a1.z, a1.w));
      *(uint4*)(Asn + 2048 + dA) =
          make_uint4(cvtpk(a2.x, a2.y), cvtpk(a2.z, a2.w), cvtpk(a3.x, a3.y), cvtpk(a3.z, a3.w));
    }

    __syncthreads();
  }

#pragma unroll
  for (int i = 0; i < 4; i++) {
#pragma unroll
    for (int j = 0; j < 4; j++) {
      const int n = n0 + wn * 64 + j * 16 + lr;
      const int mb = m0 + wm * 64 + i * 16 + lq * 4;
      const float bv = bias[n];
#pragma unroll
      for (int rr = 0; rr < 4; rr++) {
        float val = acc[i][j][rr] + bv;
        int m = mb + rr;
        if (EPI == 0) Cb[(size_t)m * N + n] = f2bf(val);
        else          Cf[(size_t)m * N + n] = val;
      }
    }
  }
}

// ---------------- MFMA attention ----------------
// One block per (window, head). 4 waves x 64 query rows (196 real, pad 256).
// Keys padded to 224. Aug K-dim = 96: [q' | RH 14 | RW 14 | flag | 0 0 0].
// R10: log2(e) folded into q-scale (0.18033688 = 0.125*log2e); Th x8 then
// stores log2e*(q.R); flag -30 -> bf16(-43.25); P = v_exp_f32(S') directly
// (2^x) -- deletes 224 dependent v_mul per thread. T1 XCD chunk swizzle on the
// grid (2400 = 8*300): all 12 heads of a window on one XCD -> qkv rows L2-hit.
// LDS 81408 B -> 2 blocks/CU.
#define R1P 104   // K_aug / A_aug row pitch (bf16 elems)
#define VTP 232   // V^T row pitch
#define PQP 40    // P sub-tile buffer row pitch
#define LDS_R1   (224 * R1P * 2)                 // 46592
#define LDS_VT   (64 * VTP * 2)                  // 29696  (aliases Th/Tw 28672)
#define LDS_PB   (4 * 16 * PQP * 2)              // 5120
#define LDS_TOT  (LDS_R1 + LDS_VT + LDS_PB)      // 81408  (2 blocks/CU)

__global__ __launch_bounds__(256, 2) void attn_mfma(
    const u16* __restrict__ qkv, u16* __restrict__ ao,
    const float* __restrict__ relph, const float* __restrict__ relpw,
    const float2* __restrict__ cs, const float* __restrict__ qb)
{
  extern __shared__ char smem[];
  u16*   R1  = (u16*)smem;                       // [224][R1P]
  u16*   VTb = (u16*)(smem + LDS_R1);            // V^T [64][VTP]
  u16*   Th  = VTb;                              // phase-A alias: [256][28]
  u16*   Tw  = VTb + 256 * 28;
  char*  PBr = smem + LDS_R1 + LDS_VT;           // 4 x [16][PQP] u16, wave-private

  // T1: 2400 = 8*300 -> bijective chunk per XCD; 12 heads of a window adjacent.
  const int orig = blockIdx.x;
  const int blk = (orig & 7) * 300 + (orig >> 3);
  const int w = blk / 12, h = blk % 12;
  const int tid = threadIdx.x;
  const int lane = tid & 63, wv = tid >> 6;
  const int lr = lane & 15, lq = lane >> 4;

  // window -> global coords
  const int b0 = w / 25, rw_ = w % 25;
  const int wy = (rw_ / 5) * 14, wx = (rw_ % 5) * 14;
  const int ty = tid / 14, tx = tid - ty * 14;       // valid for tid<196
  const int gh = wy + ty, gw = wx + tx;
  const bool inb = (tid < 196) && (gh < 64) && (gw < 64);
  const size_t grow = (size_t)((b0 * 64 + gh) * 64 + gw);

  // ---- phase A1: roped, scaled q -> R1 cols 0..63 (rows 0..223 only) ----
  {
    float qf[64];
    if (tid < 196) {
      if (inb) {
        const u16* qp = qkv + grow * 2304 + h * 64;
        uint4 q4[8];
#pragma unroll
        for (int u = 0; u < 8; u++) q4[u] = *(const uint4*)(qp + u * 8);
#pragma unroll
        for (int u = 0; u < 8; u++) {
          qf[u*8+0] = bflo(q4[u].x); qf[u*8+1] = bfhi(q4[u].x);
          qf[u*8+2] = bflo(q4[u].y); qf[u*8+3] = bfhi(q4[u].y);
          qf[u*8+4] = bflo(q4[u].z); qf[u*8+5] = bfhi(q4[u].z);
          qf[u*8+6] = bflo(q4[u].w); qf[u*8+7] = bfhi(q4[u].w);
        }
      } else {
        const float4* bp = (const float4*)(qb + h * 64);
#pragma unroll
        for (int u = 0; u < 16; u++) {
          float4 t4 = bp[u];
          qf[u*4+0] = t4.x; qf[u*4+1] = t4.y; qf[u*4+2] = t4.z; qf[u*4+3] = t4.w;
        }
      }
      const float2* ct = cs + tid * 32;
#pragma unroll
      for (int f = 0; f < 32; f++) {
        float2 c2 = ct[f];
        float xr = qf[2*f], xi = qf[2*f+1];
        qf[2*f]   = (xr * c2.x - xi * c2.y) * 0.18033688f;   // 0.125 * log2(e)
        qf[2*f+1] = (xr * c2.y + xi * c2.x) * 0.18033688f;
      }
    } else {
#pragma unroll
      for (int d = 0; d < 64; d++) qf[d] = 0.f;
    }
    if (tid < 224) {
      u16* dst = R1 + tid * R1P;
#pragma unroll
      for (int u = 0; u < 8; u++)
        *(uint4*)(dst + u * 8) = make_uint4(cvtpk(qf[u*8+0], qf[u*8+1]), cvtpk(qf[u*8+2], qf[u*8+3]),
                                            cvtpk(qf[u*8+4], qf[u*8+5]), cvtpk(qf[u*8+6], qf[u*8+7]));
    }
  }

  // ---- T14: issue K/V global loads NOW; latency hides under A2-A4 ----
  uint4 k4[8], v4[8];
  if (inb) {
    const u16* kp = qkv + grow * 2304 + 768 + h * 64;
    const u16* vp = qkv + grow * 2304 + 1536 + h * 64;
#pragma unroll
    for (int u = 0; u < 8; u++) k4[u] = *(const uint4*)(kp + u * 8);
#pragma unroll
    for (int u = 0; u < 8; u++) v4[u] = *(const uint4*)(vp + u * 8);
  }
  __syncthreads();

  // ---- phase A2: A-frags (q part) + T tables via MFMA; rel tables from global ----
  frag af[4][3];
#pragma unroll
  for (int i = 0; i < 4; i++)
#pragma unroll
    for (int kc = 0; kc < 2; kc++) {
      if (wv == 3 && i >= 2)   // rows 224..255: zero-padded queries, no LDS row
        af[i][kc].u = make_uint4(0u, 0u, 0u, 0u);
      else
        af[i][kc].u = *(const uint4*)(R1 + (wv * 64 + i * 16 + lr) * R1P + kc * 32 + lq * 8);
    }

#pragma unroll
  for (int n = 0; n < 2; n++) {
    f32x4 tah[4], taw[4];
#pragma unroll
    for (int i = 0; i < 4; i++) { tah[i] = f32x4{0,0,0,0}; taw[i] = f32x4{0,0,0,0}; }
    const int j = n * 16 + lr;   // rel-pos row 0..31 (27 real)
#pragma unroll
    for (int kc = 0; kc < 2; kc++) {
      float4 ha = {0,0,0,0}, hb = {0,0,0,0}, wa = {0,0,0,0}, wb2 = {0,0,0,0};
      if (j < 27) {
        const float* ph  = relph + j * 64 + kc * 32 + lq * 8;
        const float* pw2 = relpw + j * 64 + kc * 32 + lq * 8;
        ha = *(const float4*)ph;  hb  = *(const float4*)(ph + 4);
        wa = *(const float4*)pw2; wb2 = *(const float4*)(pw2 + 4);
      }
      frag bh, bw;
      bh.u = make_uint4(cvtpk(ha.x, ha.y), cvtpk(ha.z, ha.w), cvtpk(hb.x, hb.y), cvtpk(hb.z, hb.w));
      bw.u = make_uint4(cvtpk(wa.x, wa.y), cvtpk(wa.z, wa.w), cvtpk(wb2.x, wb2.y), cvtpk(wb2.z, wb2.w));
#pragma unroll
      for (int i = 0; i < 4; i++) {
        tah[i] = __builtin_amdgcn_mfma_f32_16x16x32_bf16(af[i][kc].b, bh.b, tah[i], 0, 0, 0);
        taw[i] = __builtin_amdgcn_mfma_f32_16x16x32_bf16(af[i][kc].b, bw.b, taw[i], 0, 0, 0);
      }
    }
    int jcol = n * 16 + lr;
    if (jcol < 28) {
#pragma unroll
      for (int i = 0; i < 4; i++)
#pragma unroll
        for (int r2 = 0; r2 < 4; r2++) {
          int qq = wv * 64 + i * 16 + lq * 4 + r2;
          Th[qq * 28 + jcol] = f2bf(tah[i][r2] * 8.f);   // = log2e * (q . Rh)
          Tw[qq * 28 + jcol] = f2bf(taw[i][r2] * 8.f);
        }
    }
  }
  __syncthreads();

  // ---- phase A3: gather RH/RW -> R1 cols 64..95 (rows 0..223) ----
  {
    u32 wb[16];
#pragma unroll
    for (int z = 0; z < 16; z++) wb[z] = 0;
    if (tid < 196) {
      const u16* thr = Th + tid * 28 + ty + 13;
      const u16* twr = Tw + tid * 28 + tx + 13;
#pragma unroll
      for (int p = 0; p < 7; p++) wb[p]     = (u32)thr[-(2*p)] | ((u32)thr[-(2*p+1)] << 16);
#pragma unroll
      for (int p = 0; p < 7; p++) wb[7 + p] = (u32)twr[-(2*p)] | ((u32)twr[-(2*p+1)] << 16);
    }
    wb[14] = 0xC22Du;   // col 92 = bf16(-43.25) = -30*log2e; col 93 = 0
    if (tid < 224) {
      u16* dst = R1 + tid * R1P + 64;
#pragma unroll
      for (int u = 0; u < 4; u++)
        *(uint4*)(dst + u * 8) = make_uint4(wb[u*4], wb[u*4+1], wb[u*4+2], wb[u*4+3]);
    }
  }
  __syncthreads();

  // ---- phase A4: A-frag bias chunk ----
#pragma unroll
  for (int i = 0; i < 4; i++) {
    if (wv == 3 && i >= 2)
      af[i][2].u = make_uint4(0u, 0u, 0u, 0u);
    else
      af[i][2].u = *(const uint4*)(R1 + (wv * 64 + i * 16 + lr) * R1P + 64 + lq * 8);
  }
  __syncthreads();

  // ---- phase B: K_aug -> R1 rows 0..223, V^T -> VTb (k4/v4 already in regs) ----
  if (tid < 224) {
    const bool real = tid < 196;
    u32 kw[32];
#pragma unroll
    for (int z = 0; z < 32; z++) kw[z] = 0;
    if (real) {
      float kf[64];
      if (inb) {
#pragma unroll
        for (int u = 0; u < 8; u++) {
          kf[u*8+0] = bflo(k4[u].x); kf[u*8+1] = bfhi(k4[u].x);
          kf[u*8+2] = bflo(k4[u].y); kf[u*8+3] = bfhi(k4[u].y);
          kf[u*8+4] = bflo(k4[u].z); kf[u*8+5] = bfhi(k4[u].z);
          kf[u*8+6] = bflo(k4[u].w); kf[u*8+7] = bfhi(k4[u].w);
        }
      } else {
        const float4* bp = (const float4*)(qb + 768 + h * 64);
#pragma unroll
        for (int u = 0; u < 16; u++) {
          float4 t4 = bp[u];
          kf[u*4+0] = t4.x; kf[u*4+1] = t4.y; kf[u*4+2] = t4.z; kf[u*4+3] = t4.w;
        }
      }
      const float2* ct = cs + tid * 32;
#pragma unroll
      for (int f = 0; f < 32; f++) {
        float2 c2 = ct[f];
        float xr = kf[2*f], xi = kf[2*f+1];
        kf[2*f]   = xr * c2.x - xi * c2.y;
        kf[2*f+1] = xr * c2.y + xi * c2.x;
      }
#pragma unroll
      for (int p = 0; p < 32; p++) kw[p] = cvtpk(kf[2*p], kf[2*p+1]);
    }
    // aug cols 64..95 branchless: one-hot of ky at 64..77, kx at 78..91;
    // structural pad keys (196..223) get col 92 = 1.0 (dots with A col 92 flag).
    const int tA = real ? 64 + ty : 92;
    const int tB = real ? 78 + tx : 92;
    u32 aw[16];
#pragma unroll
    for (int p = 0; p < 16; p++) {
      const int c0 = 64 + 2 * p, c1 = c0 + 1;
      u32 lo = (c0 == tA || c0 == tB) ? 0x3F80u : 0u;
      u32 hi = (c1 == tA || c1 == tB) ? 0x3F80u : 0u;
      aw[p] = lo | (hi << 16);
    }
    u16* dst = R1 + tid * R1P;
#pragma unroll
    for (int u = 0; u < 8; u++)
      *(uint4*)(dst + u * 8) = make_uint4(kw[u*4], kw[u*4+1], kw[u*4+2], kw[u*4+3]);
#pragma unroll
    for (int u = 0; u < 4; u++)
      *(uint4*)(dst + 64 + u * 8) = make_uint4(aw[u*4], aw[u*4+1], aw[u*4+2], aw[u*4+3]);

    // V^T (raw bf16 bits when from qkvb; converted when from bias)
    if (real) {
      u16* col = VTb + tid;
      if (inb) {
#pragma unroll
        for (int u = 0; u < 8; u++) {
          col[(u*8+0) * VTP] = (u16)(v4[u].x & 0xffff); col[(u*8+1) * VTP] = (u16)(v4[u].x >> 16);
          col[(u*8+2) * VTP] = (u16)(v4[u].y & 0xffff); col[(u*8+3) * VTP] = (u16)(v4[u].y >> 16);
          col[(u*8+4) * VTP] = (u16)(v4[u].z & 0xffff); col[(u*8+5) * VTP] = (u16)(v4[u].z >> 16);
          col[(u*8+6) * VTP] = (u16)(v4[u].w & 0xffff); col[(u*8+7) * VTP] = (u16)(v4[u].w >> 16);
        }
      } else {
        const float4* bp = (const float4*)(qb + 1536 + h * 64);
#pragma unroll
        for (int u = 0; u < 16; u++) {
          float4 t4 = bp[u];
          col[(u*4+0) * VTP] = f2bf(t4.x); col[(u*4+1) * VTP] = f2bf(t4.y);
          col[(u*4+2) * VTP] = f2bf(t4.z); col[(u*4+3) * VTP] = f2bf(t4.w);
        }
      }
    } else {
#pragma unroll
      for (int d = 0; d < 64; d++) VTb[d * VTP + tid] = 0;
    }
  }
  __syncthreads();

  // ---- main loop: 7 chunks of 32 keys, barrier-free ----
  f32x4 oacc[4][4];
  f32x4 lacc[4];
#pragma unroll
  for (int i = 0; i < 4; i++) {
    lacc[i] = f32x4{0,0,0,0};
#pragma unroll
    for (int j = 0; j < 4; j++) oacc[i][j] = f32x4{0,0,0,0};
  }
  frag ones;
  ones.u = make_uint4(0x3F803F80u, 0x3F803F80u, 0x3F803F80u, 0x3F803F80u);
  u16* PB = (u16*)PBr + wv * 16 * PQP;   // wave-private 16x40 sub-tile buffer

  for (int c = 0; c < 7; c++) {
    frag bk[2][3];
#pragma unroll
    for (int kt = 0; kt < 2; kt++)
#pragma unroll
      for (int kc = 0; kc < 3; kc++)
        bk[kt][kc].u = *(const uint4*)(R1 + (c * 32 + kt * 16 + lr) * R1P + kc * 32 + lq * 8);

    frag bv[4];
#pragma unroll
    for (int j = 0; j < 4; j++)
      bv[j].u = *(const uint4*)(VTb + (j * 16 + lr) * VTP + c * 32 + lq * 8);

    f32x4 sacc[4][2];
#pragma unroll
    for (int i = 0; i < 4; i++) { sacc[i][0] = f32x4{0,0,0,0}; sacc[i][1] = f32x4{0,0,0,0}; }
#pragma unroll
    for (int kc = 0; kc < 3; kc++)
#pragma unroll
      for (int i = 0; i < 4; i++)
#pragma unroll
        for (int kt = 0; kt < 2; kt++)
          sacc[i][kt] = __builtin_amdgcn_mfma_f32_16x16x32_bf16(af[i][kc].b, bk[kt][kc].b, sacc[i][kt], 0, 0, 0);

    // per 16x32 sub-tile: P = 2^(S') -> wave-private LDS (C-layout store,
    // A-layout read), consumed immediately by l/PV MFMAs.
#pragma unroll
    for (int i = 0; i < 4; i++) {
#pragma unroll
      for (int kt = 0; kt < 2; kt++)
#pragma unroll
        for (int r2 = 0; r2 < 4; r2++)
          PB[(lq * 4 + r2) * PQP + kt * 16 + lr] = f2bf(exp2h(sacc[i][kt][r2]));

      frag pf;
      pf.u = *(const uint4*)(PB + lr * PQP + lq * 8);

      lacc[i] = __builtin_amdgcn_mfma_f32_16x16x32_bf16(pf.b, ones.b, lacc[i], 0, 0, 0);
#pragma unroll
      for (int j = 0; j < 4; j++)
        oacc[i][j] = __builtin_amdgcn_mfma_f32_16x16x32_bf16(pf.b, bv[j].b, oacc[i][j], 0, 0, 0);
    }
  }

  // ---- epilogue: O / l -> ao token-major [32768][768] bf16 ----
#pragma unroll
  for (int i = 0; i < 4; i++) {
    f32x4 inv;
#pragma unroll
    for (int r2 = 0; r2 < 4; r2++) inv[r2] = 1.f / lacc[i][r2];
#pragma unroll
    for (int r2 = 0; r2 < 4; r2++) {
      int qq = wv * 64 + i * 16 + lq * 4 + r2;
      if (qq < 196) {
        int qy = qq / 14, qx = qq - qy * 14;
        int gh2 = wy + qy, gw2 = wx + qx;
        if (gh2 < 64 && gw2 < 64) {
          u16* op = ao + (size_t)((b0 * 64 + gh2) * 64 + gw2) * 768 + h * 64 + lr;
#pragma unroll
          for (int j = 0; j < 4; j++)
            op[j * 16] = f2bf(oacc[i][j][r2] * inv[r2]);
        }
      }
    }
  }
}

extern "C" void kernel_launch(void* const* d_in, const int* in_sizes, int n_in,
                              void* d_out, int out_size, void* d_ws, size_t ws_size,
                              hipStream_t stream) {
  const float* x      = (const float*)d_in[0];
  const float* qkv_w  = (const float*)d_in[1];
  const float* qkv_b  = (const float*)d_in[2];
  const float* proj_w = (const float*)d_in[3];
  const float* proj_b = (const float*)d_in[4];
  const float* rel_h  = (const float*)d_in[5];
  const float* rel_w  = (const float*)d_in[6];
  float* out = (float*)d_out;

  char* ws = (char*)d_ws;
  u16* qkvb = (u16*)ws;                                         // [32768][2304] bf16 = 151 MB
  u16* ao   = (u16*)(ws + (size_t)M32 * 2304 * 2);              // [32768][768] bf16 = 48 MB
  u16* qwb  = (u16*)(ws + (size_t)M32 * 2304 * 2 + (size_t)M32 * 768 * 2);
  u16* pwb  = qwb + 2304 * 768;
  float2* cs = (float2*)(pwb + 768 * 768);

  prep_w<<<6912, 256, 0, stream>>>(qkv_w, proj_w, qwb, pwb, cs);
  gemm_bt<0><<<dim3(256 * 18), 256, 0, stream>>>(x, qwb, qkv_b, qkvb, nullptr, 768, 2304, 18);
  attn_mfma<<<2400, 256, LDS_TOT, stream>>>(qkvb, ao, rel_h, rel_w, cs, qkv_b);
  gemm_bt<1><<<dim3(256 * 6), 256, 0, stream>>>(ao, pwb, proj_b, nullptr, out, 768, 768, 6);
}

// Round 11
// 504.694 us; speedup vs baseline: 1.0731x; 1.0731x over previous
//
#include <hip/hip_runtime.h>

using u16 = unsigned short;
using u32 = unsigned int;

typedef __bf16 bf16x8 __attribute__((ext_vector_type(8)));
typedef float f32x4 __attribute__((ext_vector_type(4)));

#define M32 32768   // real tokens: 8*64*64 (no window padding anywhere)

__device__ __forceinline__ u16 f2bf(float f) {
  u32 u = __float_as_uint(f);
  u += 0x7fffu + ((u >> 16) & 1u);   // RNE
  return (u16)(u >> 16);
}
__device__ __forceinline__ u32 cvtpk(float a, float b) {   // HW RNE pair convert (lo=a, hi=b)
  u32 r; asm("v_cvt_pk_bf16_f32 %0, %1, %2" : "=v"(r) : "v"(a), "v"(b)); return r;
}
__device__ __forceinline__ float bflo(u32 w) { return __uint_as_float(w << 16); }
__device__ __forceinline__ float bfhi(u32 w) { return __uint_as_float(w & 0xffff0000u); }

__device__ __forceinline__ float exp2h(float x) {          // raw v_exp_f32 (computes 2^x)
#if __has_builtin(__builtin_amdgcn_exp2f)
  return __builtin_amdgcn_exp2f(x);
#else
  float e; asm("v_exp_f32 %0, %1\n\ts_nop 0" : "=v"(e) : "v"(x)); return e;
#endif
}

__device__ __forceinline__ void async16(const void* g, void* l) {
  __builtin_amdgcn_global_load_lds((const __attribute__((address_space(1))) void*)g,
                                   (__attribute__((address_space(3))) void*)l, 16, 0, 0);
}

union frag { uint4 u; bf16x8 b; };

// ---------------- prep: weights fp32 -> bf16, rope cos/sin table ----------------
__global__ __launch_bounds__(256) void prep_w(const float* __restrict__ qw,
                                              const float* __restrict__ pw,
                                              u16* __restrict__ qwb, u16* __restrict__ pwb,
                                              float2* __restrict__ cs) {
  int i = blockIdx.x * 256 + threadIdx.x;
  if (i < 2304 * 768) qwb[i] = f2bf(qw[i]);
  if (i < 768 * 768)  pwb[i] = f2bf(pw[i]);
  if (i < 196 * 32) {
    int t = i >> 5, f = i & 31;
    float fr = powf(10000.f, -(float)(f & 15) * (1.f / 16.f));
    float ang = (f < 16 ? (float)(t % 14) : (float)(t / 14)) * fr;
    cs[i] = make_float2(cosf(ang), sinf(ang));
  }
}

// ---------------- prep_x: x fp32 [32768][768] -> bf16 (one pass, HBM-bound ~20us) ----------------
// R11: lets gemm<0>'s A-path use global_load_lds (R8 measured the reg+ds_write
// A-path costs ~60us vs async16 on gemm<1>; x being fp32 forced that path).
__global__ __launch_bounds__(256) void prep_x(const float* __restrict__ x, u16* __restrict__ xb) {
  size_t i = ((size_t)blockIdx.x * 256 + threadIdx.x) * 8;
  float4 a = *(const float4*)(x + i);
  float4 b = *(const float4*)(x + i + 4);
  *(uint4*)(xb + i) = make_uint4(cvtpk(a.x, a.y), cvtpk(a.z, a.w),
                                 cvtpk(b.x, b.y), cvtpk(b.z, b.w));
}

// ---------------- NT GEMM (128x128, BK=32, 2-phase dbuf, pure global_load_lds) ----------------
// R11: A is bf16 for BOTH instantiations -> A-path = B-path = async16 staging
// through the subtiled-swizzled LDS map (R10: 0 bank conflicts; rule 21:
// linear LDS dest + inverse-swizzled global source + swizzled frag reads).
// 2-phase double-buffer, one __syncthreads per K-step (best measured schedule:
// R7/R9). EPI only selects the C-store: EPI=0 -> qkvb bf16, EPI=1 -> out fp32.
// T1 XCD-bijective chunk swizzle, n innermost.
template<int EPI>
__global__ __launch_bounds__(256) void gemm_bt(
    const u16* __restrict__ A, const u16* __restrict__ B,
    const float* __restrict__ bias, u16* __restrict__ Cb,
    float* __restrict__ Cf, int K, int N, int NTI)
{
  __shared__ u16 As[2][128 * 32];
  __shared__ u16 Bs[2][128 * 32];

  const int nwg = gridDim.x;
  const int orig = blockIdx.x;
  const int q = nwg >> 3, r = nwg & 7;
  const int xcd = orig & 7, loc = orig >> 3;
  const int wg = (xcd < r ? xcd * (q + 1) : r * (q + 1) + (xcd - r) * q) + loc;
  const int m0 = (wg / NTI) * 128;
  const int n0 = (wg % NTI) * 128;

  const int tid = threadIdx.x;
  const int lane = tid & 63;
  const int wv = tid >> 6;
  const int wm = wv >> 1, wn = wv & 1;
  const int lr = lane & 15, lq = lane >> 4;

  // staging: LDS-linear 16B granule L = c*256+tid; inverse-swizzled source:
  // row = (tid>>6)*16 + ((tid>>2)&15)  (+64 for the second chunk),
  // col-granule = (tid&3) ^ (((tid>>5)&1)<<1)
  const int srow0 = ((tid >> 6) << 4) + ((tid >> 2) & 15);
  const int sgsw  = ((tid & 3) ^ (((tid >> 5) & 1) << 1)) * 8;
  const u16* A0 = A + (size_t)(m0 + srow0) * K + sgsw;
  const u16* B0 = B + (size_t)(n0 + srow0) * K + sgsw;

  // frag-read offset (elems): subtiled layout, XOR'd granule select
  const int fro = lr * 32 + ((lq ^ (((lr >> 3) & 1) << 1)) << 3);

  // prologue: tile 0 -> buf 0
  async16(A0, (void*)(As[0] + tid * 8));
  async16(A0 + (size_t)64 * K, (void*)(As[0] + 2048 + tid * 8));
  async16(B0, (void*)(Bs[0] + tid * 8));
  async16(B0 + (size_t)64 * K, (void*)(Bs[0] + 2048 + tid * 8));
  __syncthreads();

  f32x4 acc[4][4];
#pragma unroll
  for (int i = 0; i < 4; i++)
#pragma unroll
    for (int j = 0; j < 4; j++)
      acc[i][j] = f32x4{0.f, 0.f, 0.f, 0.f};

  const int NT = K / 32;
  for (int t = 0; t < NT; ++t) {
    const int cur = t & 1;
    const u16* Asc = As[cur];
    const u16* Bsc = Bs[cur];
    u16* Asn = As[cur ^ 1];
    u16* Bsn = Bs[cur ^ 1];
    const bool pre = (t + 1) < NT;
    const int k1 = (t + 1) * 32;

    if (pre) {
      async16(A0 + k1, (void*)(Asn + tid * 8));
      async16(A0 + (size_t)64 * K + k1, (void*)(Asn + 2048 + tid * 8));
      async16(B0 + k1, (void*)(Bsn + tid * 8));
      async16(B0 + (size_t)64 * K + k1, (void*)(Bsn + 2048 + tid * 8));
    }

    frag af[4], bg[4];
#pragma unroll
    for (int i = 0; i < 4; i++) {
      af[i].u = *(const uint4*)(Asc + (wm * 4 + i) * 512 + fro);
      bg[i].u = *(const uint4*)(Bsc + (wn * 4 + i) * 512 + fro);
    }

#pragma unroll
    for (int i = 0; i < 4; i++)
#pragma unroll
      for (int j = 0; j < 4; j++)
        acc[i][j] = __builtin_amdgcn_mfma_f32_16x16x32_bf16(af[i].b, bg[j].b, acc[i][j], 0, 0, 0);

    __syncthreads();
  }

#pragma unroll
  for (int i = 0; i < 4; i++) {
#pragma unroll
    for (int j = 0; j < 4; j++) {
      const int n = n0 + wn * 64 + j * 16 + lr;
      const int mb = m0 + wm * 64 + i * 16 + lq * 4;
      const float bv = bias[n];
#pragma unroll
      for (int rr = 0; rr < 4; rr++) {
        float val = acc[i][j][rr] + bv;
        int m = mb + rr;
        if (EPI == 0) Cb[(size_t)m * N + n] = f2bf(val);
        else          Cf[(size_t)m * N + n] = val;
      }
    }
  }
}

// ---------------- MFMA attention (unchanged from R10) ----------------
// One block per (window, head). 4 waves x 64 query rows (196 real, pad 256).
// Keys padded to 224. Aug K-dim = 96: [q' | RH 14 | RW 14 | flag | 0 0 0].
// log2(e) folded into q-scale; P = v_exp_f32(S') directly. T1 XCD chunk swizzle
// (2400 = 8*300): 12 heads of a window on one XCD -> qkv rows L2-hit.
// LDS 81408 B -> 2 blocks/CU.
#define R1P 104   // K_aug / A_aug row pitch (bf16 elems)
#define VTP 232   // V^T row pitch
#define PQP 40    // P sub-tile buffer row pitch
#define LDS_R1   (224 * R1P * 2)                 // 46592
#define LDS_VT   (64 * VTP * 2)                  // 29696  (aliases Th/Tw 28672)
#define LDS_PB   (4 * 16 * PQP * 2)              // 5120
#define LDS_TOT  (LDS_R1 + LDS_VT + LDS_PB)      // 81408  (2 blocks/CU)

__global__ __launch_bounds__(256, 2) void attn_mfma(
    const u16* __restrict__ qkv, u16* __restrict__ ao,
    const float* __restrict__ relph, const float* __restrict__ relpw,
    const float2* __restrict__ cs, const float* __restrict__ qb)
{
  extern __shared__ char smem[];
  u16*   R1  = (u16*)smem;                       // [224][R1P]
  u16*   VTb = (u16*)(smem + LDS_R1);            // V^T [64][VTP]
  u16*   Th  = VTb;                              // phase-A alias: [256][28]
  u16*   Tw  = VTb + 256 * 28;
  char*  PBr = smem + LDS_R1 + LDS_VT;           // 4 x [16][PQP] u16, wave-private

  const int orig = blockIdx.x;
  const int blk = (orig & 7) * 300 + (orig >> 3);
  const int w = blk / 12, h = blk % 12;
  const int tid = threadIdx.x;
  const int lane = tid & 63, wv = tid >> 6;
  const int lr = lane & 15, lq = lane >> 4;

  // window -> global coords
  const int b0 = w / 25, rw_ = w % 25;
  const int wy = (rw_ / 5) * 14, wx = (rw_ % 5) * 14;
  const int ty = tid / 14, tx = tid - ty * 14;       // valid for tid<196
  const int gh = wy + ty, gw = wx + tx;
  const bool inb = (tid < 196) && (gh < 64) && (gw < 64);
  const size_t grow = (size_t)((b0 * 64 + gh) * 64 + gw);

  // ---- phase A1: roped, scaled q -> R1 cols 0..63 (rows 0..223 only) ----
  {
    float qf[64];
    if (tid < 196) {
      if (inb) {
        const u16* qp = qkv + grow * 2304 + h * 64;
        uint4 q4[8];
#pragma unroll
        for (int u = 0; u < 8; u++) q4[u] = *(const uint4*)(qp + u * 8);
#pragma unroll
        for (int u = 0; u < 8; u++) {
          qf[u*8+0] = bflo(q4[u].x); qf[u*8+1] = bfhi(q4[u].x);
          qf[u*8+2] = bflo(q4[u].y); qf[u*8+3] = bfhi(q4[u].y);
          qf[u*8+4] = bflo(q4[u].z); qf[u*8+5] = bfhi(q4[u].z);
          qf[u*8+6] = bflo(q4[u].w); qf[u*8+7] = bfhi(q4[u].w);
        }
      } else {
        const float4* bp = (const float4*)(qb + h * 64);
#pragma unroll
        for (int u = 0; u < 16; u++) {
          float4 t4 = bp[u];
          qf[u*4+0] = t4.x; qf[u*4+1] = t4.y; qf[u*4+2] = t4.z; qf[u*4+3] = t4.w;
        }
      }
      const float2* ct = cs + tid * 32;
#pragma unroll
      for (int f = 0; f < 32; f++) {
        float2 c2 = ct[f];
        float xr = qf[2*f], xi = qf[2*f+1];
        qf[2*f]   = (xr * c2.x - xi * c2.y) * 0.18033688f;   // 0.125 * log2(e)
        qf[2*f+1] = (xr * c2.y + xi * c2.x) * 0.18033688f;
      }
    } else {
#pragma unroll
      for (int d = 0; d < 64; d++) qf[d] = 0.f;
    }
    if (tid < 224) {
      u16* dst = R1 + tid * R1P;
#pragma unroll
      for (int u = 0; u < 8; u++)
        *(uint4*)(dst + u * 8) = make_uint4(cvtpk(qf[u*8+0], qf[u*8+1]), cvtpk(qf[u*8+2], qf[u*8+3]),
                                            cvtpk(qf[u*8+4], qf[u*8+5]), cvtpk(qf[u*8+6], qf[u*8+7]));
    }
  }

  // ---- T14: issue K/V global loads NOW; latency hides under A2-A4 ----
  uint4 k4[8], v4[8];
  if (inb) {
    const u16* kp = qkv + grow * 2304 + 768 + h * 64;
    const u16* vp = qkv + grow * 2304 + 1536 + h * 64;
#pragma unroll
    for (int u = 0; u < 8; u++) k4[u] = *(const uint4*)(kp + u * 8);
#pragma unroll
    for (int u = 0; u < 8; u++) v4[u] = *(const uint4*)(vp + u * 8);
  }
  __syncthreads();

  // ---- phase A2: A-frags (q part) + T tables via MFMA; rel tables from global ----
  frag af[4][3];
#pragma unroll
  for (int i = 0; i < 4; i++)
#pragma unroll
    for (int kc = 0; kc < 2; kc++) {
      if (wv == 3 && i >= 2)   // rows 224..255: zero-padded queries, no LDS row
        af[i][kc].u = make_uint4(0u, 0u, 0u, 0u);
      else
        af[i][kc].u = *(const uint4*)(R1 + (wv * 64 + i * 16 + lr) * R1P + kc * 32 + lq * 8);
    }

#pragma unroll
  for (int n = 0; n < 2; n++) {
    f32x4 tah[4], taw[4];
#pragma unroll
    for (int i = 0; i < 4; i++) { tah[i] = f32x4{0,0,0,0}; taw[i] = f32x4{0,0,0,0}; }
    const int j = n * 16 + lr;   // rel-pos row 0..31 (27 real)
#pragma unroll
    for (int kc = 0; kc < 2; kc++) {
      float4 ha = {0,0,0,0}, hb = {0,0,0,0}, wa = {0,0,0,0}, wb2 = {0,0,0,0};
      if (j < 27) {
        const float* ph  = relph + j * 64 + kc * 32 + lq * 8;
        const float* pw2 = relpw + j * 64 + kc * 32 + lq * 8;
        ha = *(const float4*)ph;  hb  = *(const float4*)(ph + 4);
        wa = *(const float4*)pw2; wb2 = *(const float4*)(pw2 + 4);
      }
      frag bh, bw;
      bh.u = make_uint4(cvtpk(ha.x, ha.y), cvtpk(ha.z, ha.w), cvtpk(hb.x, hb.y), cvtpk(hb.z, hb.w));
      bw.u = make_uint4(cvtpk(wa.x, wa.y), cvtpk(wa.z, wa.w), cvtpk(wb2.x, wb2.y), cvtpk(wb2.z, wb2.w));
#pragma unroll
      for (int i = 0; i < 4; i++) {
        tah[i] = __builtin_amdgcn_mfma_f32_16x16x32_bf16(af[i][kc].b, bh.b, tah[i], 0, 0, 0);
        taw[i] = __builtin_amdgcn_mfma_f32_16x16x32_bf16(af[i][kc].b, bw.b, taw[i], 0, 0, 0);
      }
    }
    int jcol = n * 16 + lr;
    if (jcol < 28) {
#pragma unroll
      for (int i = 0; i < 4; i++)
#pragma unroll
        for (int r2 = 0; r2 < 4; r2++) {
          int qq = wv * 64 + i * 16 + lq * 4 + r2;
          Th[qq * 28 + jcol] = f2bf(tah[i][r2] * 8.f);   // = log2e * (q . Rh)
          Tw[qq * 28 + jcol] = f2bf(taw[i][r2] * 8.f);
        }
    }
  }
  __syncthreads();

  // ---- phase A3: gather RH/RW -> R1 cols 64..95 (rows 0..223) ----
  {
    u32 wb[16];
#pragma unroll
    for (int z = 0; z < 16; z++) wb[z] = 0;
    if (tid < 196) {
      const u16* thr = Th + tid * 28 + ty + 13;
      const u16* twr = Tw + tid * 28 + tx + 13;
#pragma unroll
      for (int p = 0; p < 7; p++) wb[p]     = (u32)thr[-(2*p)] | ((u32)thr[-(2*p+1)] << 16);
#pragma unroll
      for (int p = 0; p < 7; p++) wb[7 + p] = (u32)twr[-(2*p)] | ((u32)twr[-(2*p+1)] << 16);
    }
    wb[14] = 0xC22Du;   // col 92 = bf16(-43.25) = -30*log2e; col 93 = 0
    if (tid < 224) {
      u16* dst = R1 + tid * R1P + 64;
#pragma unroll
      for (int u = 0; u < 4; u++)
        *(uint4*)(dst + u * 8) = make_uint4(wb[u*4], wb[u*4+1], wb[u*4+2], wb[u*4+3]);
    }
  }
  __syncthreads();

  // ---- phase A4: A-frag bias chunk ----
#pragma unroll
  for (int i = 0; i < 4; i++) {
    if (wv == 3 && i >= 2)
      af[i][2].u = make_uint4(0u, 0u, 0u, 0u);
    else
      af[i][2].u = *(const uint4*)(R1 + (wv * 64 + i * 16 + lr) * R1P + 64 + lq * 8);
  }
  __syncthreads();

  // ---- phase B: K_aug -> R1 rows 0..223, V^T -> VTb (k4/v4 already in regs) ----
  if (tid < 224) {
    const bool real = tid < 196;
    u32 kw[32];
#pragma unroll
    for (int z = 0; z < 32; z++) kw[z] = 0;
    if (real) {
      float kf[64];
      if (inb) {
#pragma unroll
        for (int u = 0; u < 8; u++) {
          kf[u*8+0] = bflo(k4[u].x); kf[u*8+1] = bfhi(k4[u].x);
          kf[u*8+2] = bflo(k4[u].y); kf[u*8+3] = bfhi(k4[u].y);
          kf[u*8+4] = bflo(k4[u].z); kf[u*8+5] = bfhi(k4[u].z);
          kf[u*8+6] = bflo(k4[u].w); kf[u*8+7] = bfhi(k4[u].w);
        }
      } else {
        const float4* bp = (const float4*)(qb + 768 + h * 64);
#pragma unroll
        for (int u = 0; u < 16; u++) {
          float4 t4 = bp[u];
          kf[u*4+0] = t4.x; kf[u*4+1] = t4.y; kf[u*4+2] = t4.z; kf[u*4+3] = t4.w;
        }
      }
      const float2* ct = cs + tid * 32;
#pragma unroll
      for (int f = 0; f < 32; f++) {
        float2 c2 = ct[f];
        float xr = kf[2*f], xi = kf[2*f+1];
        kf[2*f]   = xr * c2.x - xi * c2.y;
        kf[2*f+1] = xr * c2.y + xi * c2.x;
      }
#pragma unroll
      for (int p = 0; p < 32; p++) kw[p] = cvtpk(kf[2*p], kf[2*p+1]);
    }
    // aug cols 64..95 branchless: one-hot of ky at 64..77, kx at 78..91;
    // structural pad keys (196..223) get col 92 = 1.0 (dots with A col 92 flag).
    const int tA = real ? 64 + ty : 92;
    const int tB = real ? 78 + tx : 92;
    u32 aw[16];
#pragma unroll
    for (int p = 0; p < 16; p++) {
      const int c0 = 64 + 2 * p, c1 = c0 + 1;
      u32 lo = (c0 == tA || c0 == tB) ? 0x3F80u : 0u;
      u32 hi = (c1 == tA || c1 == tB) ? 0x3F80u : 0u;
      aw[p] = lo | (hi << 16);
    }
    u16* dst = R1 + tid * R1P;
#pragma unroll
    for (int u = 0; u < 8; u++)
      *(uint4*)(dst + u * 8) = make_uint4(kw[u*4], kw[u*4+1], kw[u*4+2], kw[u*4+3]);
#pragma unroll
    for (int u = 0; u < 4; u++)
      *(uint4*)(dst + 64 + u * 8) = make_uint4(aw[u*4], aw[u*4+1], aw[u*4+2], aw[u*4+3]);

    // V^T (raw bf16 bits when from qkvb; converted when from bias)
    if (real) {
      u16* col = VTb + tid;
      if (inb) {
#pragma unroll
        for (int u = 0; u < 8; u++) {
          col[(u*8+0) * VTP] = (u16)(v4[u].x & 0xffff); col[(u*8+1) * VTP] = (u16)(v4[u].x >> 16);
          col[(u*8+2) * VTP] = (u16)(v4[u].y & 0xffff); col[(u*8+3) * VTP] = (u16)(v4[u].y >> 16);
          col[(u*8+4) * VTP] = (u16)(v4[u].z & 0xffff); col[(u*8+5) * VTP] = (u16)(v4[u].z >> 16);
          col[(u*8+6) * VTP] = (u16)(v4[u].w & 0xffff); col[(u*8+7) * VTP] = (u16)(v4[u].w >> 16);
        }
      } else {
        const float4* bp = (const float4*)(qb + 1536 + h * 64);
#pragma unroll
        for (int u = 0; u < 16; u++) {
          float4 t4 = bp[u];
          col[(u*4+0) * VTP] = f2bf(t4.x); col[(u*4+1) * VTP] = f2bf(t4.y);
          col[(u*4+2) * VTP] = f2bf(t4.z); col[(u*4+3) * VTP] = f2bf(t4.w);
        }
      }
    } else {
#pragma unroll
      for (int d = 0; d < 64; d++) VTb[d * VTP + tid] = 0;
    }
  }
  __syncthreads();

  // ---- main loop: 7 chunks of 32 keys, barrier-free ----
  f32x4 oacc[4][4];
  f32x4 lacc[4];
#pragma unroll
  for (int i = 0; i < 4; i++) {
    lacc[i] = f32x4{0,0,0,0};
#pragma unroll
    for (int j = 0; j < 4; j++) oacc[i][j] = f32x4{0,0,0,0};
  }
  frag ones;
  ones.u = make_uint4(0x3F803F80u, 0x3F803F80u, 0x3F803F80u, 0x3F803F80u);
  u16* PB = (u16*)PBr + wv * 16 * PQP;   // wave-private 16x40 sub-tile buffer

  for (int c = 0; c < 7; c++) {
    frag bk[2][3];
#pragma unroll
    for (int kt = 0; kt < 2; kt++)
#pragma unroll
      for (int kc = 0; kc < 3; kc++)
        bk[kt][kc].u = *(const uint4*)(R1 + (c * 32 + kt * 16 + lr) * R1P + kc * 32 + lq * 8);

    frag bv[4];
#pragma unroll
    for (int j = 0; j < 4; j++)
      bv[j].u = *(const uint4*)(VTb + (j * 16 + lr) * VTP + c * 32 + lq * 8);

    f32x4 sacc[4][2];
#pragma unroll
    for (int i = 0; i < 4; i++) { sacc[i][0] = f32x4{0,0,0,0}; sacc[i][1] = f32x4{0,0,0,0}; }
#pragma unroll
    for (int kc = 0; kc < 3; kc++)
#pragma unroll
      for (int i = 0; i < 4; i++)
#pragma unroll
        for (int kt = 0; kt < 2; kt++)
          sacc[i][kt] = __builtin_amdgcn_mfma_f32_16x16x32_bf16(af[i][kc].b, bk[kt][kc].b, sacc[i][kt], 0, 0, 0);

    // per 16x32 sub-tile: P = 2^(S') -> wave-private LDS (C-layout store,
    // A-layout read), consumed immediately by l/PV MFMAs.
#pragma unroll
    for (int i = 0; i < 4; i++) {
#pragma unroll
      for (int kt = 0; kt < 2; kt++)
#pragma unroll
        for (int r2 = 0; r2 < 4; r2++)
          PB[(lq * 4 + r2) * PQP + kt * 16 + lr] = f2bf(exp2h(sacc[i][kt][r2]));

      frag pf;
      pf.u = *(const uint4*)(PB + lr * PQP + lq * 8);

      lacc[i] = __builtin_amdgcn_mfma_f32_16x16x32_bf16(pf.b, ones.b, lacc[i], 0, 0, 0);
#pragma unroll
      for (int j = 0; j < 4; j++)
        oacc[i][j] = __builtin_amdgcn_mfma_f32_16x16x32_bf16(pf.b, bv[j].b, oacc[i][j], 0, 0, 0);
    }
  }

  // ---- epilogue: O / l -> ao token-major [32768][768] bf16 ----
#pragma unroll
  for (int i = 0; i < 4; i++) {
    f32x4 inv;
#pragma unroll
    for (int r2 = 0; r2 < 4; r2++) inv[r2] = 1.f / lacc[i][r2];
#pragma unroll
    for (int r2 = 0; r2 < 4; r2++) {
      int qq = wv * 64 + i * 16 + lq * 4 + r2;
      if (qq < 196) {
        int qy = qq / 14, qx = qq - qy * 14;
        int gh2 = wy + qy, gw2 = wx + qx;
        if (gh2 < 64 && gw2 < 64) {
          u16* op = ao + (size_t)((b0 * 64 + gh2) * 64 + gw2) * 768 + h * 64 + lr;
#pragma unroll
          for (int j = 0; j < 4; j++)
            op[j * 16] = f2bf(oacc[i][j][r2] * inv[r2]);
        }
      }
    }
  }
}

extern "C" void kernel_launch(void* const* d_in, const int* in_sizes, int n_in,
                              void* d_out, int out_size, void* d_ws, size_t ws_size,
                              hipStream_t stream) {
  const float* x      = (const float*)d_in[0];
  const float* qkv_w  = (const float*)d_in[1];
  const float* qkv_b  = (const float*)d_in[2];
  const float* proj_w = (const float*)d_in[3];
  const float* proj_b = (const float*)d_in[4];
  const float* rel_h  = (const float*)d_in[5];
  const float* rel_w  = (const float*)d_in[6];
  float* out = (float*)d_out;

  char* ws = (char*)d_ws;
  u16* qkvb = (u16*)ws;                                         // [32768][2304] bf16 = 151 MB
  u16* ao   = (u16*)(ws + (size_t)M32 * 2304 * 2);              // [32768][768] bf16 = 48 MB
  u16* qwb  = (u16*)(ws + (size_t)M32 * 2304 * 2 + (size_t)M32 * 768 * 2);
  u16* pwb  = qwb + 2304 * 768;
  float2* cs = (float2*)(pwb + 768 * 768);

  // xb (bf16 x) aliases the ao region: dead after gemm<0>, attn overwrites it.
  u16* xb = ao;

  prep_w<<<6912, 256, 0, stream>>>(qkv_w, proj_w, qwb, pwb, cs);
  prep_x<<<12288, 256, 0, stream>>>(x, xb);
  gemm_bt<0><<<dim3(256 * 18), 256, 0, stream>>>(xb, qwb, qkv_b, qkvb, nullptr, 768, 2304, 18);
  attn_mfma<<<2400, 256, LDS_TOT, stream>>>(qkvb, ao, rel_h, rel_w, cs, qkv_b);
  gemm_bt<1><<<dim3(256 * 6), 256, 0, stream>>>(ao, pwb, proj_b, nullptr, out, 768, 768, 6);
}

// Round 12
// 498.582 us; speedup vs baseline: 1.0862x; 1.0123x over previous
//
#include <hip/hip_runtime.h>

using u16 = unsigned short;
using u32 = unsigned int;

typedef __bf16 bf16x8 __attribute__((ext_vector_type(8)));
typedef float f32x4 __attribute__((ext_vector_type(4)));

#define M32 32768   // real tokens: 8*64*64 (no window padding anywhere)

__device__ __forceinline__ u16 f2bf(float f) {
  u32 u = __float_as_uint(f);
  u += 0x7fffu + ((u >> 16) & 1u);   // RNE
  return (u16)(u >> 16);
}
__device__ __forceinline__ u32 cvtpk(float a, float b) {   // HW RNE pair convert (lo=a, hi=b)
  u32 r; asm("v_cvt_pk_bf16_f32 %0, %1, %2" : "=v"(r) : "v"(a), "v"(b)); return r;
}
__device__ __forceinline__ float bflo(u32 w) { return __uint_as_float(w << 16); }
__device__ __forceinline__ float bfhi(u32 w) { return __uint_as_float(w & 0xffff0000u); }

__device__ __forceinline__ float exp2h(float x) {          // raw v_exp_f32 (computes 2^x)
#if __has_builtin(__builtin_amdgcn_exp2f)
  return __builtin_amdgcn_exp2f(x);
#else
  float e; asm("v_exp_f32 %0, %1\n\ts_nop 0" : "=v"(e) : "v"(x)); return e;
#endif
}

__device__ __forceinline__ void async16(const void* g, void* l) {
  __builtin_amdgcn_global_load_lds((const __attribute__((address_space(1))) void*)g,
                                   (__attribute__((address_space(3))) void*)l, 16, 0, 0);
}

union frag { uint4 u; bf16x8 b; };

// ---------------- fused prep: x fp32->bf16 + weights fp32->bf16 + rope table ----------------
// R12: one launch instead of two (prep_x grid 12288 | prep_w grid 6912).
__global__ __launch_bounds__(256) void prep(const float* __restrict__ x, u16* __restrict__ xb,
                                            const float* __restrict__ qw, const float* __restrict__ pw,
                                            u16* __restrict__ qwb, u16* __restrict__ pwb,
                                            float2* __restrict__ cs) {
  int bid = blockIdx.x;
  if (bid < 12288) {
    size_t i = ((size_t)bid * 256 + threadIdx.x) * 8;
    float4 a = *(const float4*)(x + i);
    float4 b = *(const float4*)(x + i + 4);
    *(uint4*)(xb + i) = make_uint4(cvtpk(a.x, a.y), cvtpk(a.z, a.w),
                                   cvtpk(b.x, b.y), cvtpk(b.z, b.w));
  } else {
    int i = (bid - 12288) * 256 + threadIdx.x;
    if (i < 2304 * 768) qwb[i] = f2bf(qw[i]);
    if (i < 768 * 768)  pwb[i] = f2bf(pw[i]);
    if (i < 196 * 32) {
      int t = i >> 5, f = i & 31;
      float fr = powf(10000.f, -(float)(f & 15) * (1.f / 16.f));
      float ang = (f < 16 ? (float)(t % 14) : (float)(t / 14)) * fr;
      cs[i] = make_float2(cosf(ang), sinf(ang));
    }
  }
}

// ---------------- NT GEMM (128x128, BK=32, triple-buffer + counted-vmcnt barrier) ----------------
// R12 (T4, clean form): both operands pure global_load_lds -> triple-buffer LDS
// (3 x 16KB = 48KB), tile t+2's 8 loads issued at iter t, barrier = s_waitcnt
// vmcnt(8) + raw s_barrier. Load->use distance = 2 iterations (~2x compute
// phase of HBM-latency cover); the newest 8 loads are NEVER drained mid-loop.
// Hazards: buf[t%3] drained at iter t-1's vmcnt(8) (t's loads oldest of 16);
// buf[(t+2)%3] untouched until t+2; post-barrier stages can't race pre-barrier
// ds_reads (barrier orders all waves' reads first). Epilogue: vmcnt(0).
// Subtiled-swizzled LDS map (R10: 0 bank conflicts), T1 XCD chunk swizzle.
//  EPI=0: C = qkvb bf16 linear.  EPI=1: C = out fp32 linear.
template<int EPI>
__global__ __launch_bounds__(256) void gemm_bt(
    const u16* __restrict__ A, const u16* __restrict__ B,
    const float* __restrict__ bias, u16* __restrict__ Cb,
    float* __restrict__ Cf, int K, int N, int NTI)
{
  __shared__ u16 As[3][128 * 32];
  __shared__ u16 Bs[3][128 * 32];

  const int nwg = gridDim.x;
  const int orig = blockIdx.x;
  const int q = nwg >> 3, r = nwg & 7;
  const int xcd = orig & 7, loc = orig >> 3;
  const int wg = (xcd < r ? xcd * (q + 1) : r * (q + 1) + (xcd - r) * q) + loc;
  const int m0 = (wg / NTI) * 128;
  const int n0 = (wg % NTI) * 128;

  const int tid = threadIdx.x;
  const int lane = tid & 63;
  const int wv = tid >> 6;
  const int wm = wv >> 1, wn = wv & 1;
  const int lr = lane & 15, lq = lane >> 4;

  // staging: LDS-linear 16B granule; inverse-swizzled source (rule 21):
  // row = (tid>>6)*16 + ((tid>>2)&15) (+64 second chunk),
  // col-granule = (tid&3) ^ (((tid>>5)&1)<<1)
  const int srow0 = ((tid >> 6) << 4) + ((tid >> 2) & 15);
  const int sgsw  = ((tid & 3) ^ (((tid >> 5) & 1) << 1)) * 8;
  const u16* A0 = A + (size_t)(m0 + srow0) * K + sgsw;
  const u16* B0 = B + (size_t)(n0 + srow0) * K + sgsw;

  // frag-read offset (elems): subtiled layout, XOR'd granule select
  const int fro = lr * 32 + ((lq ^ (((lr >> 3) & 1) << 1)) << 3);

#define STAGE(buf, kk) { \
    async16(A0 + (kk), (void*)(As[buf] + tid * 8)); \
    async16(A0 + (size_t)64 * K + (kk), (void*)(As[buf] + 2048 + tid * 8)); \
    async16(B0 + (kk), (void*)(Bs[buf] + tid * 8)); \
    async16(B0 + (size_t)64 * K + (kk), (void*)(Bs[buf] + 2048 + tid * 8)); }

  // prologue: tiles 0,1 staged; wait tile 0 (keep tile 1's 8 in flight)
  STAGE(0, 0);
  STAGE(1, 32);
  asm volatile("s_waitcnt vmcnt(8)" ::: "memory");
  __builtin_amdgcn_s_barrier();

  f32x4 acc[4][4];
#pragma unroll
  for (int i = 0; i < 4; i++)
#pragma unroll
    for (int j = 0; j < 4; j++)
      acc[i][j] = f32x4{0.f, 0.f, 0.f, 0.f};

  const int NT = K / 32;
  for (int t = 0; t < NT; ++t) {
    const int cur = t % 3;
    const int nxt = (t + 2) % 3;
    const bool pre = (t + 2) < NT;

    if (pre) STAGE(nxt, (t + 2) * 32);   // issue-first (T3): max cover

    const u16* Asc = As[cur];
    const u16* Bsc = Bs[cur];
    frag af[4], bg[4];
#pragma unroll
    for (int i = 0; i < 4; i++) {
      af[i].u = *(const uint4*)(Asc + (wm * 4 + i) * 512 + fro);
      bg[i].u = *(const uint4*)(Bsc + (wn * 4 + i) * 512 + fro);
    }

#pragma unroll
    for (int i = 0; i < 4; i++)
#pragma unroll
      for (int j = 0; j < 4; j++)
        acc[i][j] = __builtin_amdgcn_mfma_f32_16x16x32_bf16(af[i].b, bg[j].b, acc[i][j], 0, 0, 0);

    if (pre) { asm volatile("s_waitcnt vmcnt(8)" ::: "memory"); }
    else     { asm volatile("s_waitcnt vmcnt(0)" ::: "memory"); }
    __builtin_amdgcn_s_barrier();
  }
#undef STAGE

#pragma unroll
  for (int i = 0; i < 4; i++) {
#pragma unroll
    for (int j = 0; j < 4; j++) {
      const int n = n0 + wn * 64 + j * 16 + lr;
      const int mb = m0 + wm * 64 + i * 16 + lq * 4;
      const float bv = bias[n];
#pragma unroll
      for (int rr = 0; rr < 4; rr++) {
        float val = acc[i][j][rr] + bv;
        int m = mb + rr;
        if (EPI == 0) Cb[(size_t)m * N + n] = f2bf(val);
        else          Cf[(size_t)m * N + n] = val;
      }
    }
  }
}

// ---------------- MFMA attention (unchanged from R11) ----------------
// One block per (window, head). 4 waves x 64 query rows (196 real, pad 256).
// Keys padded to 224. Aug K-dim = 96: [q' | RH 14 | RW 14 | flag | 0 0 0].
// log2(e) folded into q-scale; P = v_exp_f32(S') directly. T1 XCD chunk swizzle
// (2400 = 8*300): 12 heads of a window on one XCD -> qkv rows L2-hit.
// LDS 81408 B -> 2 blocks/CU.
#define R1P 104   // K_aug / A_aug row pitch (bf16 elems)
#define VTP 232   // V^T row pitch
#define PQP 40    // P sub-tile buffer row pitch
#define LDS_R1   (224 * R1P * 2)                 // 46592
#define LDS_VT   (64 * VTP * 2)                  // 29696  (aliases Th/Tw 28672)
#define LDS_PB   (4 * 16 * PQP * 2)              // 5120
#define LDS_TOT  (LDS_R1 + LDS_VT + LDS_PB)      // 81408  (2 blocks/CU)

__global__ __launch_bounds__(256, 2) void attn_mfma(
    const u16* __restrict__ qkv, u16* __restrict__ ao,
    const float* __restrict__ relph, const float* __restrict__ relpw,
    const float2* __restrict__ cs, const float* __restrict__ qb)
{
  extern __shared__ char smem[];
  u16*   R1  = (u16*)smem;                       // [224][R1P]
  u16*   VTb = (u16*)(smem + LDS_R1);            // V^T [64][VTP]
  u16*   Th  = VTb;                              // phase-A alias: [256][28]
  u16*   Tw  = VTb + 256 * 28;
  char*  PBr = smem + LDS_R1 + LDS_VT;           // 4 x [16][PQP] u16, wave-private

  const int orig = blockIdx.x;
  const int blk = (orig & 7) * 300 + (orig >> 3);
  const int w = blk / 12, h = blk % 12;
  const int tid = threadIdx.x;
  const int lane = tid & 63, wv = tid >> 6;
  const int lr = lane & 15, lq = lane >> 4;

  // window -> global coords
  const int b0 = w / 25, rw_ = w % 25;
  const int wy = (rw_ / 5) * 14, wx = (rw_ % 5) * 14;
  const int ty = tid / 14, tx = tid - ty * 14;       // valid for tid<196
  const int gh = wy + ty, gw = wx + tx;
  const bool inb = (tid < 196) && (gh < 64) && (gw < 64);
  const size_t grow = (size_t)((b0 * 64 + gh) * 64 + gw);

  // ---- phase A1: roped, scaled q -> R1 cols 0..63 (rows 0..223 only) ----
  {
    float qf[64];
    if (tid < 196) {
      if (inb) {
        const u16* qp = qkv + grow * 2304 + h * 64;
        uint4 q4[8];
#pragma unroll
        for (int u = 0; u < 8; u++) q4[u] = *(const uint4*)(qp + u * 8);
#pragma unroll
        for (int u = 0; u < 8; u++) {
          qf[u*8+0] = bflo(q4[u].x); qf[u*8+1] = bfhi(q4[u].x);
          qf[u*8+2] = bflo(q4[u].y); qf[u*8+3] = bfhi(q4[u].y);
          qf[u*8+4] = bflo(q4[u].z); qf[u*8+5] = bfhi(q4[u].z);
          qf[u*8+6] = bflo(q4[u].w); qf[u*8+7] = bfhi(q4[u].w);
        }
      } else {
        const float4* bp = (const float4*)(qb + h * 64);
#pragma unroll
        for (int u = 0; u < 16; u++) {
          float4 t4 = bp[u];
          qf[u*4+0] = t4.x; qf[u*4+1] = t4.y; qf[u*4+2] = t4.z; qf[u*4+3] = t4.w;
        }
      }
      const float2* ct = cs + tid * 32;
#pragma unroll
      for (int f = 0; f < 32; f++) {
        float2 c2 = ct[f];
        float xr = qf[2*f], xi = qf[2*f+1];
        qf[2*f]   = (xr * c2.x - xi * c2.y) * 0.18033688f;   // 0.125 * log2(e)
        qf[2*f+1] = (xr * c2.y + xi * c2.x) * 0.18033688f;
      }
    } else {
#pragma unroll
      for (int d = 0; d < 64; d++) qf[d] = 0.f;
    }
    if (tid < 224) {
      u16* dst = R1 + tid * R1P;
#pragma unroll
      for (int u = 0; u < 8; u++)
        *(uint4*)(dst + u * 8) = make_uint4(cvtpk(qf[u*8+0], qf[u*8+1]), cvtpk(qf[u*8+2], qf[u*8+3]),
                                            cvtpk(qf[u*8+4], qf[u*8+5]), cvtpk(qf[u*8+6], qf[u*8+7]));
    }
  }

  // ---- T14: issue K/V global loads NOW; latency hides under A2-A4 ----
  uint4 k4[8], v4[8];
  if (inb) {
    const u16* kp = qkv + grow * 2304 + 768 + h * 64;
    const u16* vp = qkv + grow * 2304 + 1536 + h * 64;
#pragma unroll
    for (int u = 0; u < 8; u++) k4[u] = *(const uint4*)(kp + u * 8);
#pragma unroll
    for (int u = 0; u < 8; u++) v4[u] = *(const uint4*)(vp + u * 8);
  }
  __syncthreads();

  // ---- phase A2: A-frags (q part) + T tables via MFMA; rel tables from global ----
  frag af[4][3];
#pragma unroll
  for (int i = 0; i < 4; i++)
#pragma unroll
    for (int kc = 0; kc < 2; kc++) {
      if (wv == 3 && i >= 2)   // rows 224..255: zero-padded queries, no LDS row
        af[i][kc].u = make_uint4(0u, 0u, 0u, 0u);
      else
        af[i][kc].u = *(const uint4*)(R1 + (wv * 64 + i * 16 + lr) * R1P + kc * 32 + lq * 8);
    }

#pragma unroll
  for (int n = 0; n < 2; n++) {
    f32x4 tah[4], taw[4];
#pragma unroll
    for (int i = 0; i < 4; i++) { tah[i] = f32x4{0,0,0,0}; taw[i] = f32x4{0,0,0,0}; }
    const int j = n * 16 + lr;   // rel-pos row 0..31 (27 real)
#pragma unroll
    for (int kc = 0; kc < 2; kc++) {
      float4 ha = {0,0,0,0}, hb = {0,0,0,0}, wa = {0,0,0,0}, wb2 = {0,0,0,0};
      if (j < 27) {
        const float* ph  = relph + j * 64 + kc * 32 + lq * 8;
        const float* pw2 = relpw + j * 64 + kc * 32 + lq * 8;
        ha = *(const float4*)ph;  hb  = *(const float4*)(ph + 4);
        wa = *(const float4*)pw2; wb2 = *(const float4*)(pw2 + 4);
      }
      frag bh, bw;
      bh.u = make_uint4(cvtpk(ha.x, ha.y), cvtpk(ha.z, ha.w), cvtpk(hb.x, hb.y), cvtpk(hb.z, hb.w));
      bw.u = make_uint4(cvtpk(wa.x, wa.y), cvtpk(wa.z, wa.w), cvtpk(wb2.x, wb2.y), cvtpk(wb2.z, wb2.w));
#pragma unroll
      for (int i = 0; i < 4; i++) {
        tah[i] = __builtin_amdgcn_mfma_f32_16x16x32_bf16(af[i][kc].b, bh.b, tah[i], 0, 0, 0);
        taw[i] = __builtin_amdgcn_mfma_f32_16x16x32_bf16(af[i][kc].b, bw.b, taw[i], 0, 0, 0);
      }
    }
    int jcol = n * 16 + lr;
    if (jcol < 28) {
#pragma unroll
      for (int i = 0; i < 4; i++)
#pragma unroll
        for (int r2 = 0; r2 < 4; r2++) {
          int qq = wv * 64 + i * 16 + lq * 4 + r2;
          Th[qq * 28 + jcol] = f2bf(tah[i][r2] * 8.f);   // = log2e * (q . Rh)
          Tw[qq * 28 + jcol] = f2bf(taw[i][r2] * 8.f);
        }
    }
  }
  __syncthreads();

  // ---- phase A3: gather RH/RW -> R1 cols 64..95 (rows 0..223) ----
  {
    u32 wb[16];
#pragma unroll
    for (int z = 0; z < 16; z++) wb[z] = 0;
    if (tid < 196) {
      const u16* thr = Th + tid * 28 + ty + 13;
      const u16* twr = Tw + tid * 28 + tx + 13;
#pragma unroll
      for (int p = 0; p < 7; p++) wb[p]     = (u32)thr[-(2*p)] | ((u32)thr[-(2*p+1)] << 16);
#pragma unroll
      for (int p = 0; p < 7; p++) wb[7 + p] = (u32)twr[-(2*p)] | ((u32)twr[-(2*p+1)] << 16);
    }
    wb[14] = 0xC22Du;   // col 92 = bf16(-43.25) = -30*log2e; col 93 = 0
    if (tid < 224) {
      u16* dst = R1 + tid * R1P + 64;
#pragma unroll
      for (int u = 0; u < 4; u++)
        *(uint4*)(dst + u * 8) = make_uint4(wb[u*4], wb[u*4+1], wb[u*4+2], wb[u*4+3]);
    }
  }
  __syncthreads();

  // ---- phase A4: A-frag bias chunk ----
#pragma unroll
  for (int i = 0; i < 4; i++) {
    if (wv == 3 && i >= 2)
      af[i][2].u = make_uint4(0u, 0u, 0u, 0u);
    else
      af[i][2].u = *(const uint4*)(R1 + (wv * 64 + i * 16 + lr) * R1P + 64 + lq * 8);
  }
  __syncthreads();

  // ---- phase B: K_aug -> R1 rows 0..223, V^T -> VTb (k4/v4 already in regs) ----
  if (tid < 224) {
    const bool real = tid < 196;
    u32 kw[32];
#pragma unroll
    for (int z = 0; z < 32; z++) kw[z] = 0;
    if (real) {
      float kf[64];
      if (inb) {
#pragma unroll
        for (int u = 0; u < 8; u++) {
          kf[u*8+0] = bflo(k4[u].x); kf[u*8+1] = bfhi(k4[u].x);
          kf[u*8+2] = bflo(k4[u].y); kf[u*8+3] = bfhi(k4[u].y);
          kf[u*8+4] = bflo(k4[u].z); kf[u*8+5] = bfhi(k4[u].z);
          kf[u*8+6] = bflo(k4[u].w); kf[u*8+7] = bfhi(k4[u].w);
        }
      } else {
        const float4* bp = (const float4*)(qb + 768 + h * 64);
#pragma unroll
        for (int u = 0; u < 16; u++) {
          float4 t4 = bp[u];
          kf[u*4+0] = t4.x; kf[u*4+1] = t4.y; kf[u*4+2] = t4.z; kf[u*4+3] = t4.w;
        }
      }
      const float2* ct = cs + tid * 32;
#pragma unroll
      for (int f = 0; f < 32; f++) {
        float2 c2 = ct[f];
        float xr = kf[2*f], xi = kf[2*f+1];
        kf[2*f]   = xr * c2.x - xi * c2.y;
        kf[2*f+1] = xr * c2.y + xi * c2.x;
      }
#pragma unroll
      for (int p = 0; p < 32; p++) kw[p] = cvtpk(kf[2*p], kf[2*p+1]);
    }
    // aug cols 64..95 branchless: one-hot of ky at 64..77, kx at 78..91;
    // structural pad keys (196..223) get col 92 = 1.0 (dots with A col 92 flag).
    const int tA = real ? 64 + ty : 92;
    const int tB = real ? 78 + tx : 92;
    u32 aw[16];
#pragma unroll
    for (int p = 0; p < 16; p++) {
      const int c0 = 64 + 2 * p, c1 = c0 + 1;
      u32 lo = (c0 == tA || c0 == tB) ? 0x3F80u : 0u;
      u32 hi = (c1 == tA || c1 == tB) ? 0x3F80u : 0u;
      aw[p] = lo | (hi << 16);
    }
    u16* dst = R1 + tid * R1P;
#pragma unroll
    for (int u = 0; u < 8; u++)
      *(uint4*)(dst + u * 8) = make_uint4(kw[u*4], kw[u*4+1], kw[u*4+2], kw[u*4+3]);
#pragma unroll
    for (int u = 0; u < 4; u++)
      *(uint4*)(dst + 64 + u * 8) = make_uint4(aw[u*4], aw[u*4+1], aw[u*4+2], aw[u*4+3]);

    // V^T (raw bf16 bits when from qkvb; converted when from bias)
    if (real) {
      u16* col = VTb + tid;
      if (inb) {
#pragma unroll
        for (int u = 0; u < 8; u++) {
          col[(u*8+0) * VTP] = (u16)(v4[u].x & 0xffff); col[(u*8+1) * VTP] = (u16)(v4[u].x >> 16);
          col[(u*8+2) * VTP] = (u16)(v4[u].y & 0xffff); col[(u*8+3) * VTP] = (u16)(v4[u].y >> 16);
          col[(u*8+4) * VTP] = (u16)(v4[u].z & 0xffff); col[(u*8+5) * VTP] = (u16)(v4[u].z >> 16);
          col[(u*8+6) * VTP] = (u16)(v4[u].w & 0xffff); col[(u*8+7) * VTP] = (u16)(v4[u].w >> 16);
        }
      } else {
        const float4* bp = (const float4*)(qb + 1536 + h * 64);
#pragma unroll
        for (int u = 0; u < 16; u++) {
          float4 t4 = bp[u];
          col[(u*4+0) * VTP] = f2bf(t4.x); col[(u*4+1) * VTP] = f2bf(t4.y);
          col[(u*4+2) * VTP] = f2bf(t4.z); col[(u*4+3) * VTP] = f2bf(t4.w);
        }
      }
    } else {
#pragma unroll
      for (int d = 0; d < 64; d++) VTb[d * VTP + tid] = 0;
    }
  }
  __syncthreads();

  // ---- main loop: 7 chunks of 32 keys, barrier-free ----
  f32x4 oacc[4][4];
  f32x4 lacc[4];
#pragma unroll
  for (int i = 0; i < 4; i++) {
    lacc[i] = f32x4{0,0,0,0};
#pragma unroll
    for (int j = 0; j < 4; j++) oacc[i][j] = f32x4{0,0,0,0};
  }
  frag ones;
  ones.u = make_uint4(0x3F803F80u, 0x3F803F80u, 0x3F803F80u, 0x3F803F80u);
  u16* PB = (u16*)PBr + wv * 16 * PQP;   // wave-private 16x40 sub-tile buffer

  for (int c = 0; c < 7; c++) {
    frag bk[2][3];
#pragma unroll
    for (int kt = 0; kt < 2; kt++)
#pragma unroll
      for (int kc = 0; kc < 3; kc++)
        bk[kt][kc].u = *(const uint4*)(R1 + (c * 32 + kt * 16 + lr) * R1P + kc * 32 + lq * 8);

    frag bv[4];
#pragma unroll
    for (int j = 0; j < 4; j++)
      bv[j].u = *(const uint4*)(VTb + (j * 16 + lr) * VTP + c * 32 + lq * 8);

    f32x4 sacc[4][2];
#pragma unroll
    for (int i = 0; i < 4; i++) { sacc[i][0] = f32x4{0,0,0,0}; sacc[i][1] = f32x4{0,0,0,0}; }
#pragma unroll
    for (int kc = 0; kc < 3; kc++)
#pragma unroll
      for (int i = 0; i < 4; i++)
#pragma unroll
        for (int kt = 0; kt < 2; kt++)
          sacc[i][kt] = __builtin_amdgcn_mfma_f32_16x16x32_bf16(af[i][kc].b, bk[kt][kc].b, sacc[i][kt], 0, 0, 0);

    // per 16x32 sub-tile: P = 2^(S') -> wave-private LDS (C-layout store,
    // A-layout read), consumed immediately by l/PV MFMAs.
#pragma unroll
    for (int i = 0; i < 4; i++) {
#pragma unroll
      for (int kt = 0; kt < 2; kt++)
#pragma unroll
        for (int r2 = 0; r2 < 4; r2++)
          PB[(lq * 4 + r2) * PQP + kt * 16 + lr] = f2bf(exp2h(sacc[i][kt][r2]));

      frag pf;
      pf.u = *(const uint4*)(PB + lr * PQP + lq * 8);

      lacc[i] = __builtin_amdgcn_mfma_f32_16x16x32_bf16(pf.b, ones.b, lacc[i], 0, 0, 0);
#pragma unroll
      for (int j = 0; j < 4; j++)
        oacc[i][j] = __builtin_amdgcn_mfma_f32_16x16x32_bf16(pf.b, bv[j].b, oacc[i][j], 0, 0, 0);
    }
  }

  // ---- epilogue: O / l -> ao token-major [32768][768] bf16 ----
#pragma unroll
  for (int i = 0; i < 4; i++) {
    f32x4 inv;
#pragma unroll
    for (int r2 = 0; r2 < 4; r2++) inv[r2] = 1.f / lacc[i][r2];
#pragma unroll
    for (int r2 = 0; r2 < 4; r2++) {
      int qq = wv * 64 + i * 16 + lq * 4 + r2;
      if (qq < 196) {
        int qy = qq / 14, qx = qq - qy * 14;
        int gh2 = wy + qy, gw2 = wx + qx;
        if (gh2 < 64 && gw2 < 64) {
          u16* op = ao + (size_t)((b0 * 64 + gh2) * 64 + gw2) * 768 + h * 64 + lr;
#pragma unroll
          for (int j = 0; j < 4; j++)
            op[j * 16] = f2bf(oacc[i][j][r2] * inv[r2]);
        }
      }
    }
  }
}

extern "C" void kernel_launch(void* const* d_in, const int* in_sizes, int n_in,
                              void* d_out, int out_size, void* d_ws, size_t ws_size,
                              hipStream_t stream) {
  const float* x      = (const float*)d_in[0];
  const float* qkv_w  = (const float*)d_in[1];
  const float* qkv_b  = (const float*)d_in[2];
  const float* proj_w = (const float*)d_in[3];
  const float* proj_b = (const float*)d_in[4];
  const float* rel_h  = (const float*)d_in[5];
  const float* rel_w  = (const float*)d_in[6];
  float* out = (float*)d_out;

  char* ws = (char*)d_ws;
  u16* qkvb = (u16*)ws;                                         // [32768][2304] bf16 = 151 MB
  u16* ao   = (u16*)(ws + (size_t)M32 * 2304 * 2);              // [32768][768] bf16 = 48 MB
  u16* qwb  = (u16*)(ws + (size_t)M32 * 2304 * 2 + (size_t)M32 * 768 * 2);
  u16* pwb  = qwb + 2304 * 768;
  float2* cs = (float2*)(pwb + 768 * 768);

  // xb (bf16 x) aliases the ao region: dead after gemm<0>, attn overwrites it.
  u16* xb = ao;

  prep<<<19200, 256, 0, stream>>>(x, xb, qkv_w, proj_w, qwb, pwb, cs);
  gemm_bt<0><<<dim3(256 * 18), 256, 0, stream>>>(xb, qwb, qkv_b, qkvb, nullptr, 768, 2304, 18);
  attn_mfma<<<2400, 256, LDS_TOT, stream>>>(qkvb, ao, rel_h, rel_w, cs, qkv_b);
  gemm_bt<1><<<dim3(256 * 6), 256, 0, stream>>>(ao, pwb, proj_b, nullptr, out, 768, 768, 6);
}